// Round 2
// 889.919 us; speedup vs baseline: 1.1045x; 1.1045x over previous
//
#include <hip/hip_runtime.h>
#include <cstdint>
#include <cstddef>

#define C_    128
#define T_    300
#define V_    25
#define TT    2
#define KA    3
#define KDIM  384
#define B2P   136           // per-k-slice B2 pitch (shorts): 128+8, rows 272 B (16B-aligned)
#define ALP   40            // Albf v-pitch
#define XTP   40            // xt v-pitch (zero-padded v>=25)
#define NSLOT 64
#define NTOT  64

// LDS layout (units: shorts):
//   Albf [3][32][40]  @ 0      (3840 sh,  7680 B)   A^T bf16, zero-padded
//   xt   [2][128][40] @ 3840   (10240 sh, 20480 B)  x tile bf16, zero-padded
//   B2   [64][136]    @ 14080  (8704 sh,  17408 B)  one 128-wide kd-slice of X'
//   total 22784 sh = 45568 B  -> 3 blocks/CU (136,704 B <= 160K)
//   Zs fp32 [128][50] aliases Albf+xt (25600 B <= 28160 B)
#define ALBF_O 0
#define XT_O   3840
#define B2_O   14080
#define SH_TOT 22784

typedef __attribute__((ext_vector_type(8))) short short8;
typedef __attribute__((ext_vector_type(4))) short short4v;
typedef __attribute__((ext_vector_type(4))) float float4v;
typedef __attribute__((ext_vector_type(2))) float float2v;

__device__ __forceinline__ short f2bf(float f) {
  union { float f; uint32_t u; } v; v.f = f;
  uint32_t r = (v.u + 0x7FFFu + ((v.u >> 16) & 1u)) >> 16;
  return (short)(uint16_t)r;
}
__device__ __forceinline__ float bf2f(short s) {
  union { uint32_t u; float f; } v; v.u = ((uint32_t)(uint16_t)s) << 16;
  return v.f;
}

// ---------------- K0: precompute W2 (bf16, [c][k*128+c']), bias2, zero stats
__global__ __launch_bounds__(256) void k0_prep(const float* __restrict__ W,
    const float* __restrict__ A, const float* __restrict__ b,
    short* __restrict__ W2, float* __restrict__ bias2, float* __restrict__ stats)
{
  int e = blockIdx.x * 256 + threadIdx.x;
  if (e < C_*KDIM) {                         // W2[c][kd] = W[k*128+c][c']
    int c = e / KDIM, kd = e % KDIM;
    int k = kd >> 7, c2 = kd & 127;
    W2[e] = f2bf(W[(k*C_ + c)*C_ + c2]);
  } else if (e < C_*KDIM + C_*32) {          // bias2[c][w] = sum_k b[kC+c]*colsumA[k][w]
    int i = e - C_*KDIM;
    int c = i >> 5, w = i & 31;
    float val = 0.f;
    if (w < V_) {
      for (int k = 0; k < KA; ++k) {
        float cs = 0.f;
        for (int v = 0; v < V_; ++v) cs += A[(k*V_ + v)*V_ + w];
        val += b[k*C_ + c] * cs;
      }
    }
    bias2[i] = val;
  } else if (e < C_*KDIM + C_*32 + 2*NSLOT*C_) {  // zero stat floats
    stats[e - (C_*KDIM + C_*32)] = 0.f;
  }
}

// ---------------- K1: fused agg-MFMA -> conv-MFMA -> residual+relu -> out + BN partials
// 3 k-passes over B2 slice (128 kd each); W2 fragments register-prefetched per pass.
__global__ __launch_bounds__(256, 3) void k1_main(const float* __restrict__ x,
    const float* __restrict__ A, const short* __restrict__ W2,
    const float* __restrict__ bias2, float* __restrict__ ssum,
    float* __restrict__ ssq, float* __restrict__ out)
{
  __shared__ __align__(16) short SH[SH_TOT];
  short* Albf_ = SH + ALBF_O;   // [k][w][v]  : k*1280 + w*40 + v
  short* xt_   = SH + XT_O;     // [t][c][v]  : t*5120 + c*40 + v
  short* B2_   = SH + B2_O;     // [pos][c']  : pos*136 + c2

  const int tid  = threadIdx.x;
  const int lane = tid & 63;
  const int wid  = tid >> 6;
  const int l15  = lane & 15;
  const int quad = lane >> 4;
  const int nb = blockIdx.x;
  const int n  = nb / (T_/TT);
  const int tb = nb % (T_/TT);
  const int t0 = tb * TT;

  // Albf fill
  for (int i = tid; i < KA*32*ALP; i += 256) {
    int k = i / (32*ALP);
    int rem = i % (32*ALP);
    int w = rem / ALP;
    int v = rem % ALP;
    float a = (w < V_ && v < V_) ? A[(k*V_ + v)*V_ + w] : 0.f;
    Albf_[i] = f2bf(a);
  }
  // xt pad zero: v in [25,40)
  for (int i = tid; i < TT*C_*15; i += 256) {
    int t = i / (C_*15);
    int r = i % (C_*15);
    int c = r / 15;
    int v = V_ + (r % 15);
    xt_[t*5120 + c*XTP + v] = 0;
  }
  // xt fill: coalesced float2 loads of x tile (128 c' x 50 floats)
  {
    const float* xb = x + (((size_t)n*C_)*T_ + t0)*V_;
    for (int p = tid; p < 3200; p += 256) {
      int c = (p*5243) >> 17;       // p/25
      int r = p - c*25;             // float2 index within the 50-float segment
      float2v xv = *(const float2v*)(xb + (size_t)c*(T_*V_) + 2*r);
      int j0 = 2*r;
      { int j = j0;   int t = (j >= V_); int v = j - t*V_; xt_[t*5120 + c*XTP + v] = f2bf(xv[0]); }
      { int j = j0+1; int t = (j >= V_); int v = j - t*V_; xt_[t*5120 + c*XTP + v] = f2bf(xv[1]); }
    }
  }
  __syncthreads();

  // per-wave roles
  const int mh = wid >> 1;      // stage1: c' half
  const int tW = wid & 1;       // stage1: t within tile
  const int wm = wid >> 1;      // stage2: c half (64 rows)
  const int wn = wid & 1;       // stage2: pos half (32 cols)

  float4v acc[4][2];
  #pragma unroll
  for (int mi = 0; mi < 4; ++mi)
    #pragma unroll
    for (int ni = 0; ni < 2; ++ni)
      acc[mi][ni] = (float4v){0.f, 0.f, 0.f, 0.f};

  short8 w2r[4][4];
  const short* w2base = W2 + (size_t)(wm*64 + l15)*KDIM + quad*8;

  for (int k = 0; k < KA; ++k) {
    // prefetch this pass's W2 fragments (consumed after the barrier; latency
    // overlaps stage-1 compute + barrier wait)
    #pragma unroll
    for (int ks = 0; ks < 4; ++ks)
      #pragma unroll
      for (int mi = 0; mi < 4; ++mi)
        w2r[ks][mi] = *(const short8*)(w2base + (size_t)mi*16*KDIM + k*C_ + ks*32);

    // ---- stage 1 (this k-slice): X'[c'][t*32+w] = sum_v x[c',t,v]*A[k,v,w]
    {
      short8 bf0 = *(const short8*)&Albf_[k*1280 + l15*ALP + quad*8];
      short8 bf1 = *(const short8*)&Albf_[k*1280 + (16 + l15)*ALP + quad*8];
      #pragma unroll
      for (int mi4 = 0; mi4 < 4; ++mi4) {
        int m8 = mh*4 + mi4;
        short8 af = *(const short8*)&xt_[tW*5120 + (m8*16 + l15)*XTP + quad*8];
        int c2 = m8*16 + quad*4;
        #pragma unroll
        for (int ni = 0; ni < 2; ++ni) {
          float4v s1 = {0.f, 0.f, 0.f, 0.f};
          s1 = __builtin_amdgcn_mfma_f32_16x16x32_bf16(af, ni ? bf1 : bf0, s1, 0, 0, 0);
          short4v sv;
          sv[0] = f2bf(s1[0]); sv[1] = f2bf(s1[1]);
          sv[2] = f2bf(s1[2]); sv[3] = f2bf(s1[3]);
          int pos = tW*32 + ni*16 + l15;
          *(short4v*)&B2_[pos*B2P + c2] = sv;
        }
      }
    }
    __syncthreads();

    // ---- stage 2: acc += W2[:,k-slice] * B2
    #pragma unroll
    for (int ks = 0; ks < 4; ++ks) {
      short8 b0 = *(const short8*)&B2_[(wn*32 + l15)*B2P + ks*32 + quad*8];
      short8 b1 = *(const short8*)&B2_[(wn*32 + 16 + l15)*B2P + ks*32 + quad*8];
      #pragma unroll
      for (int mi = 0; mi < 4; ++mi) {
        acc[mi][0] = __builtin_amdgcn_mfma_f32_16x16x32_bf16(w2r[ks][mi], b0, acc[mi][0], 0, 0, 0);
        acc[mi][1] = __builtin_amdgcn_mfma_f32_16x16x32_bf16(w2r[ks][mi], b1, acc[mi][1], 0, 0, 0);
      }
    }
    if (k < KA-1) __syncthreads();   // protect B2 before next stage-1 write
  }

  // ---- epilogue: +bias2, +x residual (LDS), relu; BN partials; z kept in acc
  float lsum[4][4], lsq[4][4];
  #pragma unroll
  for (int a1 = 0; a1 < 4; ++a1)
    #pragma unroll
    for (int a2 = 0; a2 < 4; ++a2) { lsum[a1][a2] = 0.f; lsq[a1][a2] = 0.f; }

  #pragma unroll
  for (int ni = 0; ni < 2; ++ni) {
    int pos = wn*32 + ni*16 + l15;
    int t = pos >> 5;
    int w = pos & 31;
    if (w < V_) {
      #pragma unroll
      for (int mi = 0; mi < 4; ++mi) {
        int cb = wm*64 + mi*16 + quad*4;
        #pragma unroll
        for (int r = 0; r < 4; ++r) {
          int cc = cb + r;
          float z = acc[mi][ni][r] + bias2[cc*32 + w];
          z += bf2f(xt_[t*5120 + cc*XTP + w]);
          z = fmaxf(z, 0.f);
          acc[mi][ni][r] = z;
          lsum[mi][r] += z;
          lsq[mi][r]  += z*z;
        }
      }
    }
  }

  __syncthreads();   // all xt residual reads complete; safe to alias Albf+xt as Zs
  float* Zs = (float*)SH;          // [128][50] fp32 = 25.6 KB

  #pragma unroll
  for (int ni = 0; ni < 2; ++ni) {
    int pos = wn*32 + ni*16 + l15;
    int t = pos >> 5;
    int w = pos & 31;
    if (w < V_) {
      #pragma unroll
      for (int mi = 0; mi < 4; ++mi) {
        int cb = wm*64 + mi*16 + quad*4;
        #pragma unroll
        for (int r = 0; r < 4; ++r) {
          Zs[(cb + r)*50 + t*V_ + w] = acc[mi][ni][r];
        }
      }
    }
  }
  __syncthreads();

  // coalesced cooperative store of Z tile to out
  {
    float* ob = out + (((size_t)n*C_)*T_ + t0)*V_;
    for (int p = tid; p < 3200; p += 256) {
      int c = (p*5243) >> 17;       // p/25
      int r = p - c*25;
      float2v zz = *(const float2v*)&Zs[c*50 + 2*r];
      *(float2v*)(ob + (size_t)c*(T_*V_) + 2*r) = zz;
    }
  }

  // BN partial sums
  int slot = nb & (NSLOT - 1);
  #pragma unroll
  for (int mi = 0; mi < 4; ++mi) {
    #pragma unroll
    for (int r = 0; r < 4; ++r) {
      float s = lsum[mi][r];
      float q = lsq[mi][r];
      #pragma unroll
      for (int m = 1; m <= 8; m <<= 1) {
        s += __shfl_xor(s, m, 64);
        q += __shfl_xor(q, m, 64);
      }
      if (l15 == 0) {
        int cc = wm*64 + mi*16 + quad*4 + r;
        atomicAdd(&ssum[slot*C_ + cc], s);
        atomicAdd(&ssq[slot*C_ + cc], q);
      }
    }
  }
}

// ---------------- K2: finalize BN scale/shift; copy A to output tail
__global__ __launch_bounds__(256) void k2_stats(const float* __restrict__ ssum,
    const float* __restrict__ ssq, const float* __restrict__ gamma,
    const float* __restrict__ beta, const float* __restrict__ A,
    float* __restrict__ sscale, float* __restrict__ sshift, float* __restrict__ outA)
{
  int id = blockIdx.x * 256 + threadIdx.x;
  if (id < C_) {
    float s = 0.f, q = 0.f;
    for (int sl = 0; sl < NSLOT; ++sl) { s += ssum[sl*C_ + id]; q += ssq[sl*C_ + id]; }
    const float cnt = 480000.f;   // N*T*V
    float mean = s / cnt;
    float var  = q / cnt - mean*mean;
    float inv  = rsqrtf(var + 1e-5f);
    float sc   = gamma[id] * inv;
    sscale[id] = sc;
    sshift[id] = beta[id] - mean * sc;
  } else if (id < C_ + KA*V_*V_) {
    int i = id - C_;
    outA[i] = A[i];
  }
}

// ---------------- K3: in-place BN apply; block = (n, 4-t chunk), branch-free float4 RMW
// 64 n x 75 chunks (300/4 exact) = 4800 blocks; 8 blocks/CU resident, 12.5 iters/thread.
__global__ __launch_bounds__(256) void k3_bn(float* __restrict__ out,
    const float* __restrict__ sscale, const float* __restrict__ sshift)
{
  __shared__ float s_sc[C_], s_sh[C_];
  int tid = threadIdx.x;
  if (tid < C_) s_sc[tid] = sscale[tid];
  else          s_sh[tid - C_] = sshift[tid - C_];
  __syncthreads();

  int n = blockIdx.x / 75;
  int chunk = blockIdx.x % 75;
  float* base = out + (size_t)n*C_*T_*V_ + chunk*100;   // 4 t-rows = 100 floats per c

  int f = tid;
  #pragma unroll 4
  for (int it = 0; it < 12; ++it, f += 256) {
    int c = (f*5243) >> 17;       // f/25
    int r = f - c*25;
    float4v* p = (float4v*)(base + (size_t)c*(T_*V_) + 4*r);
    float4v v = *p;
    float sc = s_sc[c], sh = s_sh[c];
    v[0] = v[0]*sc + sh; v[1] = v[1]*sc + sh;
    v[2] = v[2]*sc + sh; v[3] = v[3]*sc + sh;
    *p = v;
  }
  if (f < 3200) {                  // tail: tid < 128
    int c = (f*5243) >> 17;
    int r = f - c*25;
    float4v* p = (float4v*)(base + (size_t)c*(T_*V_) + 4*r);
    float4v v = *p;
    float sc = s_sc[c], sh = s_sh[c];
    v[0] = v[0]*sc + sh; v[1] = v[1]*sc + sh;
    v[2] = v[2]*sc + sh; v[3] = v[3]*sc + sh;
    *p = v;
  }
}

extern "C" void kernel_launch(void* const* d_in, const int* in_sizes, int n_in,
                              void* d_out, int out_size, void* d_ws, size_t ws_size,
                              hipStream_t stream)
{
  const float* x     = (const float*)d_in[0];
  const float* A     = (const float*)d_in[1];
  const float* W     = (const float*)d_in[2];
  const float* b     = (const float*)d_in[3];
  const float* gamma = (const float*)d_in[4];
  const float* beta  = (const float*)d_in[5];
  float* out = (float*)d_out;

  short* W2    = (short*)d_ws;                          // 98,304 B
  float* bias2 = (float*)((char*)d_ws + 98304);         // 16,384 B
  float* stats = (float*)((char*)d_ws + 114688);        // 65,536 B (sum|sq)
  float* ssum   = stats;
  float* ssq    = stats + NSLOT*C_;
  float* sscale = stats + 2*NSLOT*C_;
  float* sshift = sscale + C_;
  float* outA = out + (size_t)NTOT*C_*T_*V_;            // A tail at 61,440,000

  k0_prep <<<272,   256, 0, stream>>>(W, A, b, W2, bias2, stats);
  k1_main <<<9600,  256, 0, stream>>>(x, A, W2, bias2, ssum, ssq, out);
  k2_stats<<<8,     256, 0, stream>>>(ssum, ssq, gamma, beta, A, sscale, sshift, outA);
  k3_bn   <<<4800,  256, 0, stream>>>(out, sscale, sshift);
}

// Round 3
// 851.646 us; speedup vs baseline: 1.1541x; 1.0449x over previous
//
#include <hip/hip_runtime.h>
#include <cstdint>
#include <cstddef>

#define C_    128
#define T_    300
#define V_    25
#define TT    2
#define KA    3
#define KDIM  384
#define ALP   40            // Albf v-pitch
#define XTP   40            // xt v-pitch (zero-padded v>=25)
#define NSLOT 64
#define NTOT  64

// LDS layout (units: shorts):
//   Albf [3][32][40]  @ 0      (3840 sh,  7680 B)   A^T bf16, zero-padded
//   xt   [2][128][40] @ 3840   (10240 sh, 20480 B)  x tile bf16, zero-padded
//   total 14080 sh = 28160 B  -> LDS allows 5 blocks/CU; VGPR(<=128) -> 4
// No B2: stage1 -> stage2 goes through registers (shfl quad-permute).
#define ALBF_O 0
#define XT_O   3840
#define SH_TOT 14080

typedef __attribute__((ext_vector_type(8))) short short8;
typedef __attribute__((ext_vector_type(4))) float float4v;
typedef __attribute__((ext_vector_type(2))) float float2v;

__device__ __forceinline__ short f2bf(float f) {
  union { float f; uint32_t u; } v; v.f = f;
  uint32_t r = (v.u + 0x7FFFu + ((v.u >> 16) & 1u)) >> 16;
  return (short)(uint16_t)r;
}
__device__ __forceinline__ float bf2f(short s) {
  union { uint32_t u; float f; } v; v.u = ((uint32_t)(uint16_t)s) << 16;
  return v.f;
}
__device__ __forceinline__ uint32_t pk2(float lo, float hi) {
  return (uint32_t)(uint16_t)f2bf(lo) | ((uint32_t)(uint16_t)f2bf(hi) << 16);
}

// ---------------- K0: precompute W2 (bf16, [c][k*128+c']), bias2, zero stats
__global__ __launch_bounds__(256) void k0_prep(const float* __restrict__ W,
    const float* __restrict__ A, const float* __restrict__ b,
    short* __restrict__ W2, float* __restrict__ bias2, float* __restrict__ stats)
{
  int e = blockIdx.x * 256 + threadIdx.x;
  if (e < C_*KDIM) {                         // W2[c][kd] = W[k*128+c][c']
    int c = e / KDIM, kd = e % KDIM;
    int k = kd >> 7, c2 = kd & 127;
    W2[e] = f2bf(W[(k*C_ + c)*C_ + c2]);
  } else if (e < C_*KDIM + C_*32) {          // bias2[c][w] = sum_k b[kC+c]*colsumA[k][w]
    int i = e - C_*KDIM;
    int c = i >> 5, w = i & 31;
    float val = 0.f;
    if (w < V_) {
      for (int k = 0; k < KA; ++k) {
        float cs = 0.f;
        for (int v = 0; v < V_; ++v) cs += A[(k*V_ + v)*V_ + w];
        val += b[k*C_ + c] * cs;
      }
    }
    bias2[i] = val;
  } else if (e < C_*KDIM + C_*32 + 2*NSLOT*C_) {  // zero stat floats
    stats[e - (C_*KDIM + C_*32)] = 0.f;
  }
}

// ---------------- K1: fused agg-MFMA -> (register shuffle) -> conv-MFMA -> epilogue
// ONE barrier per block. Each wave (wm,wn) owns c-half wm, pos-half (=t) wn and
// recomputes stage-1 for its own pos-half; B-fragments assembled via 8 shfl + 4 sel.
__global__ __launch_bounds__(256, 4) void k1_main(const float* __restrict__ x,
    const float* __restrict__ A, const short* __restrict__ W2,
    const float* __restrict__ bias2, float* __restrict__ ssum,
    float* __restrict__ ssq, float* __restrict__ out)
{
  __shared__ __align__(16) short SH[SH_TOT];
  short* Albf_ = SH + ALBF_O;   // [k][w][v]  : k*1280 + w*40 + v
  short* xt_   = SH + XT_O;     // [t][c][v]  : t*5120 + c*40 + v

  const int tid  = threadIdx.x;
  const int lane = tid & 63;
  const int wid  = tid >> 6;       // 4 waves
  const int l15  = lane & 15;
  const int quad = lane >> 4;
  const int nb = blockIdx.x;
  const int n  = nb / (T_/TT);
  const int tb = nb % (T_/TT);
  const int t0 = tb * TT;

  // Albf fill
  for (int i = tid; i < KA*32*ALP; i += 256) {
    int k = i / (32*ALP);
    int rem = i % (32*ALP);
    int w = rem / ALP;
    int v = rem % ALP;
    float a = (w < V_ && v < V_) ? A[(k*V_ + v)*V_ + w] : 0.f;
    Albf_[i] = f2bf(a);
  }
  // xt pad zero: v in [25,40)
  for (int i = tid; i < TT*C_*15; i += 256) {
    int t = i / (C_*15);
    int r = i % (C_*15);
    int c = r / 15;
    int v = V_ + (r % 15);
    xt_[t*5120 + c*XTP + v] = 0;
  }
  // xt fill: coalesced float2 loads of x tile (128 c' x 50 floats)
  {
    const float* xb = x + (((size_t)n*C_)*T_ + t0)*V_;
    for (int p = tid; p < 3200; p += 256) {
      int c = (p*5243) >> 17;       // p/25
      int r = p - c*25;             // float2 index within the 50-float segment
      float2v xv = *(const float2v*)(xb + (size_t)c*(T_*V_) + 2*r);
      int j0 = 2*r;
      { int j = j0;   int t = (j >= V_); int v = j - t*V_; xt_[t*5120 + c*XTP + v] = f2bf(xv[0]); }
      { int j = j0+1; int t = (j >= V_); int v = j - t*V_; xt_[t*5120 + c*XTP + v] = f2bf(xv[1]); }
    }
  }
  __syncthreads();       // the ONLY barrier

  const int wm = wid >> 1;      // c half (64 rows)
  const int wn = wid & 1;       // pos half (32 cols) == t within tile

  float4v acc[4][2];
  #pragma unroll
  for (int mi = 0; mi < 4; ++mi)
    #pragma unroll
    for (int ni = 0; ni < 2; ++ni)
      acc[mi][ni] = (float4v){0.f, 0.f, 0.f, 0.f};

  const short* w2base = W2 + (size_t)(wm*64 + l15)*KDIM + quad*8;
  const int s0 = ((quad & 1) << 5) + l15;   // source lane for B-frag words 0,1
  const int s1 = s0 + 16;                   // source lane for B-frag words 2,3
  const int hi = quad >> 1;                 // 0: take tileA, 1: take tileB

  // main loop: 12 kd-chunks of 32 (kd = k*128 + cb), barrier-free
  #pragma unroll 2
  for (int kc = 0; kc < 12; ++kc) {
    const int k  = kc >> 2;
    const int cb = (kc & 3) * 32;
    const int kb = k*C_ + cb;

    // stage-2 A fragments (W2 rows, from L2) — issued early, consumed late
    short8 w2f[4];
    #pragma unroll
    for (int mi = 0; mi < 4; ++mi)
      w2f[mi] = *(const short8*)(w2base + (size_t)mi*16*KDIM + kb);

    // stage-1 A fragments (xt rows cb..cb+31 of this wave's t-half)
    short8 afA = *(const short8*)&xt_[wn*5120 + (cb + l15)*XTP + quad*8];
    short8 afB = *(const short8*)&xt_[wn*5120 + (cb + 16 + l15)*XTP + quad*8];

    #pragma unroll
    for (int ni = 0; ni < 2; ++ni) {
      short8 bfk = *(const short8*)&Albf_[k*1280 + (ni*16 + l15)*ALP + quad*8];
      float4v dA = {0.f,0.f,0.f,0.f}, dB = {0.f,0.f,0.f,0.f};
      dA = __builtin_amdgcn_mfma_f32_16x16x32_bf16(afA, bfk, dA, 0, 0, 0);
      dB = __builtin_amdgcn_mfma_f32_16x16x32_bf16(afB, bfk, dB, 0, 0, 0);

      // pack D to bf16 pairs: p0=(m0,m1), p1=(m2,m3) per lane
      int pA0 = (int)pk2(dA[0], dA[1]), pA1 = (int)pk2(dA[2], dA[3]);
      int pB0 = (int)pk2(dB[0], dB[1]), pB1 = (int)pk2(dB[2], dB[3]);

      // assemble stage-2 B fragment: elem j of lane(quad,l15) = X'(kb + quad*8+j, pos)
      int a0 = __shfl(pA0, s0), a1 = __shfl(pA1, s0);
      int a2 = __shfl(pA0, s1), a3 = __shfl(pA1, s1);
      int b0 = __shfl(pB0, s0), b1 = __shfl(pB1, s0);
      int b2 = __shfl(pB0, s1), b3 = __shfl(pB1, s1);
      union { short8 s; int u[4]; } bf;
      bf.u[0] = hi ? b0 : a0;
      bf.u[1] = hi ? b1 : a1;
      bf.u[2] = hi ? b2 : a2;
      bf.u[3] = hi ? b3 : a3;

      #pragma unroll
      for (int mi = 0; mi < 4; ++mi)
        acc[mi][ni] = __builtin_amdgcn_mfma_f32_16x16x32_bf16(w2f[mi], bf.s, acc[mi][ni], 0, 0, 0);
    }
  }

  // ---- epilogue: +bias2, +x residual (LDS), relu; direct store; BN partials
  float lsum[4][4], lsq[4][4];
  #pragma unroll
  for (int a1 = 0; a1 < 4; ++a1)
    #pragma unroll
    for (int a2 = 0; a2 < 4; ++a2) { lsum[a1][a2] = 0.f; lsq[a1][a2] = 0.f; }

  const int tG = t0 + wn;
  float* obase = out + (size_t)n*(C_*T_*V_) + (size_t)tG*V_;

  #pragma unroll
  for (int ni = 0; ni < 2; ++ni) {
    int w = ni*16 + l15;
    bool act = (w < V_);
    #pragma unroll
    for (int mi = 0; mi < 4; ++mi) {
      #pragma unroll
      for (int r = 0; r < 4; ++r) {
        int cc = wm*64 + mi*16 + quad*4 + r;
        float z = acc[mi][ni][r] + bias2[cc*32 + w];
        z += bf2f(xt_[wn*5120 + cc*XTP + w]);
        z = fmaxf(z, 0.f);
        if (act) {
          obase[(size_t)cc*(T_*V_) + w] = z;
          lsum[mi][r] += z;
          lsq[mi][r]  += z*z;
        }
      }
    }
  }

  // BN partial sums
  int slot = nb & (NSLOT - 1);
  #pragma unroll
  for (int mi = 0; mi < 4; ++mi) {
    #pragma unroll
    for (int r = 0; r < 4; ++r) {
      float s = lsum[mi][r];
      float q = lsq[mi][r];
      #pragma unroll
      for (int m = 1; m <= 8; m <<= 1) {
        s += __shfl_xor(s, m, 64);
        q += __shfl_xor(q, m, 64);
      }
      if (l15 == 0) {
        int cc = wm*64 + mi*16 + quad*4 + r;
        atomicAdd(&ssum[slot*C_ + cc], s);
        atomicAdd(&ssq[slot*C_ + cc], q);
      }
    }
  }
}

// ---------------- K2: finalize BN scale/shift; copy A to output tail
__global__ __launch_bounds__(256) void k2_stats(const float* __restrict__ ssum,
    const float* __restrict__ ssq, const float* __restrict__ gamma,
    const float* __restrict__ beta, const float* __restrict__ A,
    float* __restrict__ sscale, float* __restrict__ sshift, float* __restrict__ outA)
{
  int id = blockIdx.x * 256 + threadIdx.x;
  if (id < C_) {
    float s = 0.f, q = 0.f;
    for (int sl = 0; sl < NSLOT; ++sl) { s += ssum[sl*C_ + id]; q += ssq[sl*C_ + id]; }
    const float cnt = 480000.f;   // N*T*V
    float mean = s / cnt;
    float var  = q / cnt - mean*mean;
    float inv  = rsqrtf(var + 1e-5f);
    float sc   = gamma[id] * inv;
    sscale[id] = sc;
    sshift[id] = beta[id] - mean * sc;
  } else if (id < C_ + KA*V_*V_) {
    int i = id - C_;
    outA[i] = A[i];
  }
}

// ---------------- K3: in-place BN apply; block = (n, 4-t chunk), branch-free float4 RMW
__global__ __launch_bounds__(256) void k3_bn(float* __restrict__ out,
    const float* __restrict__ sscale, const float* __restrict__ sshift)
{
  __shared__ float s_sc[C_], s_sh[C_];
  int tid = threadIdx.x;
  if (tid < C_) s_sc[tid] = sscale[tid];
  else          s_sh[tid - C_] = sshift[tid - C_];
  __syncthreads();

  int n = blockIdx.x / 75;
  int chunk = blockIdx.x % 75;
  float* base = out + (size_t)n*C_*T_*V_ + chunk*100;   // 4 t-rows = 100 floats per c

  int f = tid;
  #pragma unroll 4
  for (int it = 0; it < 12; ++it, f += 256) {
    int c = (f*5243) >> 17;       // f/25
    int r = f - c*25;
    float4v* p = (float4v*)(base + (size_t)c*(T_*V_) + 4*r);
    float4v v = *p;
    float sc = s_sc[c], sh = s_sh[c];
    v[0] = v[0]*sc + sh; v[1] = v[1]*sc + sh;
    v[2] = v[2]*sc + sh; v[3] = v[3]*sc + sh;
    *p = v;
  }
  if (f < 3200) {                  // tail: tid < 128
    int c = (f*5243) >> 17;
    int r = f - c*25;
    float4v* p = (float4v*)(base + (size_t)c*(T_*V_) + 4*r);
    float4v v = *p;
    float sc = s_sc[c], sh = s_sh[c];
    v[0] = v[0]*sc + sh; v[1] = v[1]*sc + sh;
    v[2] = v[2]*sc + sh; v[3] = v[3]*sc + sh;
    *p = v;
  }
}

extern "C" void kernel_launch(void* const* d_in, const int* in_sizes, int n_in,
                              void* d_out, int out_size, void* d_ws, size_t ws_size,
                              hipStream_t stream)
{
  const float* x     = (const float*)d_in[0];
  const float* A     = (const float*)d_in[1];
  const float* W     = (const float*)d_in[2];
  const float* b     = (const float*)d_in[3];
  const float* gamma = (const float*)d_in[4];
  const float* beta  = (const float*)d_in[5];
  float* out = (float*)d_out;

  short* W2    = (short*)d_ws;                          // 98,304 B
  float* bias2 = (float*)((char*)d_ws + 98304);         // 16,384 B
  float* stats = (float*)((char*)d_ws + 114688);        // 65,536 B (sum|sq)
  float* ssum   = stats;
  float* ssq    = stats + NSLOT*C_;
  float* sscale = stats + 2*NSLOT*C_;
  float* sshift = sscale + C_;
  float* outA = out + (size_t)NTOT*C_*T_*V_;            // A tail at 61,440,000

  k0_prep <<<272,   256, 0, stream>>>(W, A, b, W2, bias2, stats);
  k1_main <<<9600,  256, 0, stream>>>(x, A, W2, bias2, ssum, ssq, out);
  k2_stats<<<8,     256, 0, stream>>>(ssum, ssq, gamma, beta, A, sscale, sshift, outA);
  k3_bn   <<<4800,  256, 0, stream>>>(out, sscale, sshift);
}